// Round 1
// baseline (314.963 us; speedup 1.0000x reference)
//
#include <hip/hip_runtime.h>
#include <stdint.h>

typedef __attribute__((ext_vector_type(8))) short shortx8;
typedef __attribute__((ext_vector_type(4))) float floatx4;

static constexpr int SEQ_    = 2048;
static constexpr int DMODEL  = 1024;
static constexpr int HDIM    = 64;
static constexpr int BATCH_  = 2;
static constexpr int NHEADS  = 16;
static constexpr int WINDOW_ = 64;
static constexpr int GTOK    = 4;
static constexpr int RTOK    = 32;
static constexpr int ROWS    = BATCH_ * SEQ_;   // 4096
static constexpr int QKVN    = 3 * DMODEL;      // 3072

__device__ inline unsigned short f2bf(float f) {
  union { float f; unsigned int u; } x; x.f = f;
  unsigned int r = (x.u + 0x7FFFu + ((x.u >> 16) & 1u)) >> 16;
  return (unsigned short)r;
}
__device__ inline float bf2f(unsigned short b) {
  union { unsigned int u; float f; } x; x.u = ((unsigned int)b) << 16;
  return x.f;
}

// ---------------- LayerNorm -> bf16 ----------------
__global__ __launch_bounds__(256) void ln_kernel(const float* __restrict__ x,
    const float* __restrict__ gamma, const float* __restrict__ beta,
    unsigned short* __restrict__ xn) {
  int row = blockIdx.x;
  int t = threadIdx.x;
  const float4* xr = (const float4*)(x + (size_t)row * DMODEL);
  float4 v = xr[t];
  float s = v.x + v.y + v.z + v.w;
  #pragma unroll
  for (int o = 32; o > 0; o >>= 1) s += __shfl_xor(s, o);
  __shared__ float red[4];
  __shared__ float red2[4];
  int wave = t >> 6, lane = t & 63;
  if (lane == 0) red[wave] = s;
  __syncthreads();
  float mean = (red[0] + red[1] + red[2] + red[3]) * (1.0f / DMODEL);
  float dx = v.x - mean, dy = v.y - mean, dz = v.z - mean, dw = v.w - mean;
  float q = dx*dx + dy*dy + dz*dz + dw*dw;
  #pragma unroll
  for (int o = 32; o > 0; o >>= 1) q += __shfl_xor(q, o);
  if (lane == 0) red2[wave] = q;
  __syncthreads();
  float var = (red2[0] + red2[1] + red2[2] + red2[3]) * (1.0f / DMODEL);
  float rs = rsqrtf(var + 1e-5f);
  float4 g = ((const float4*)gamma)[t];
  float4 bb = ((const float4*)beta)[t];
  ushort4 outv;
  outv.x = f2bf(dx * rs * g.x + bb.x);
  outv.y = f2bf(dy * rs * g.y + bb.y);
  outv.z = f2bf(dz * rs * g.z + bb.z);
  outv.w = f2bf(dw * rs * g.w + bb.w);
  ((ushort4*)(xn + (size_t)row * DMODEL))[t] = outv;
}

// ---------------- fp32 -> bf16 convert ----------------
__global__ __launch_bounds__(256) void cvt_kernel(const float* __restrict__ src,
    unsigned short* __restrict__ dst, int n4) {
  int i = blockIdx.x * blockDim.x + threadIdx.x;
  if (i < n4) {
    float4 v = ((const float4*)src)[i];
    ushort4 o;
    o.x = f2bf(v.x); o.y = f2bf(v.y); o.z = f2bf(v.z); o.w = f2bf(v.w);
    ((ushort4*)dst)[i] = o;
  }
}

// ---------------- bf16 MFMA GEMM: C[MxN] = A[MxK] @ B[KxN] (+resid) ----------------
// 64x64 block tile, BK=32, 256 threads = 4 waves (2x2), wave does 32x32 (2x2 mfma 16x16x32)
__global__ __launch_bounds__(256) void gemm_bf16(
    const unsigned short* __restrict__ A, const unsigned short* __restrict__ Bm,
    unsigned short* __restrict__ Cb, float* __restrict__ Cf,
    const float* __restrict__ resid, int M, int N, int K) {
  __shared__ unsigned short Al[64][40];   // [row][k]  pad->stride 40 (2-way max)
  __shared__ unsigned short Bl[64][40];   // [col][k]  (transposed)
  const int bm = blockIdx.y * 64, bn = blockIdx.x * 64;
  const int tid = threadIdx.x;
  const int wave = tid >> 6, lane = tid & 63;
  const int wm = (wave >> 1) * 32, wn = (wave & 1) * 32;
  const int quad = lane >> 4, l16 = lane & 15;
  floatx4 acc[2][2] = {};
  const int ar = tid >> 2, akc = (tid & 3) * 8;  // A: 64 rows x 32 k, 16B per thread
  const int bk = tid >> 3, bcc = (tid & 7) * 8;  // B: 32 k x 64 cols, 16B per thread
  for (int k0 = 0; k0 < K; k0 += 32) {
    __syncthreads();
    int4 av = *(const int4*)(A + (size_t)(bm + ar) * K + k0 + akc);
    int4 bv = *(const int4*)(Bm + (size_t)(k0 + bk) * N + bn + bcc);
    *(int4*)&Al[ar][akc] = av;
    union { int4 v; unsigned short s[8]; } bu; bu.v = bv;
    #pragma unroll
    for (int j = 0; j < 8; j++) Bl[bcc + j][bk] = bu.s[j];
    __syncthreads();
    shortx8 af[2], bfr[2];
    #pragma unroll
    for (int s = 0; s < 2; s++) {
      af[s]  = *(const shortx8*)&Al[wm + s * 16 + l16][quad * 8];
      bfr[s] = *(const shortx8*)&Bl[wn + s * 16 + l16][quad * 8];
    }
    #pragma unroll
    for (int sm = 0; sm < 2; sm++)
      #pragma unroll
      for (int sn = 0; sn < 2; sn++)
        acc[sm][sn] = __builtin_amdgcn_mfma_f32_16x16x32_bf16(af[sm], bfr[sn], acc[sm][sn], 0, 0, 0);
  }
  #pragma unroll
  for (int sm = 0; sm < 2; sm++)
    #pragma unroll
    for (int sn = 0; sn < 2; sn++)
      #pragma unroll
      for (int r = 0; r < 4; r++) {
        int row = bm + wm + sm * 16 + quad * 4 + r;
        int col = bn + wn + sn * 16 + l16;
        size_t off = (size_t)row * N + col;
        float v = acc[sm][sn][r];
        if (resid) v += resid[off];
        if (Cf) Cf[off] = v;
        else    Cb[off] = f2bf(v);
      }
}

// ---------------- per-row top-tier mask column lists ----------------
// tier(j) = local + glob + rnd (each causal). fp32 collapse => softmax is uniform
// over top-tier cols unless tier==3 (then softmax of 3*qk/8 over tier-3 cols).
__global__ __launch_bounds__(64) void mask_rows(const int* __restrict__ rand_idx,
    int* __restrict__ cols, int* __restrict__ cnt, int* __restrict__ tmx) {
  const int i = blockIdx.x;
  const int lane = threadIdx.x;
  __shared__ int rl[RTOK];
  __shared__ int scount;
  if (lane < RTOK) rl[lane] = rand_idx[i * RTOK + lane];
  if (lane == 0) scount = 0;
  __syncthreads();
  const int wstart = (i - WINDOW_ > 0) ? (i - WINDOW_) : 0;
  int jj[2]; int tt[2];
  #pragma unroll
  for (int p = 0; p < 2; p++) {
    int c = lane + p * 64;
    int j = -1;
    bool valid = false;
    if (c < 65) {                       // window candidates (includes diagonal)
      j = i - WINDOW_ + c;
      valid = (j >= 0);
    } else if (c < 73) {                // global cols not already in window
      int g = c - 65;
      j = (g < 4) ? g : (SEQ_ - 8 + g);
      valid = (j <= i) && (j < wstart);
    } else if (c < 73 + RTOK) {         // random cols not in window/global, deduped
      int r = c - 73;
      j = rl[r];
      bool dup = false;
      for (int r2 = 0; r2 < r; r2++) dup = dup || (rl[r2] == j);
      valid = (j <= i) && (j < wstart) && !(j < GTOK || j >= SEQ_ - GTOK) && !dup;
    }
    int t = -1;
    if (valid) {
      int loc = ((i - j) <= WINDOW_) ? 1 : 0;
      int glb = (j < GTOK || j >= SEQ_ - GTOK) ? 1 : 0;
      int rnd = 0;
      for (int r = 0; r < RTOK; r++) rnd |= (rl[r] == j) ? 1 : 0;
      t = loc + glb + rnd;
    }
    jj[p] = j; tt[p] = t;
  }
  int tm = (tt[0] > tt[1]) ? tt[0] : tt[1];
  #pragma unroll
  for (int o = 1; o < 64; o <<= 1) {
    int other = __shfl_xor(tm, o);
    tm = (other > tm) ? other : tm;
  }
  #pragma unroll
  for (int p = 0; p < 2; p++) {
    if (tt[p] == tm) {
      int pos = atomicAdd(&scount, 1);
      cols[i * 128 + pos] = jj[p];
    }
  }
  __syncthreads();
  if (lane == 0) { cnt[i] = scount; tmx[i] = tm; }
}

// ---------------- sparse attention: one wave per (row, b, h) ----------------
__global__ __launch_bounds__(64) void attn_sparse(
    const unsigned short* __restrict__ qkv, const int* __restrict__ cols,
    const int* __restrict__ cnt, const int* __restrict__ tmx,
    unsigned short* __restrict__ ao) {
  const int i = blockIdx.x;
  const int bh = blockIdx.y;
  const int b = bh >> 4, h = bh & 15;
  const int lane = threadIdx.x;     // = head dim d
  const int n = cnt[i];
  const int tm = tmx[i];
  __shared__ int cj[128];
  __shared__ float sw[128];
  for (int c = lane; c < n; c += 64) cj[c] = cols[i * 128 + c];
  __syncthreads();
  const size_t rowbase = (size_t)(b * SEQ_) * QKVN + (size_t)h * HDIM + lane;
  float acc = 0.0f;
  if (tm < 3) {
    // exact fp32 semantics: uniform over top-tier columns
    for (int c = 0; c < n; c++) {
      int j = cj[c];
      acc += bf2f(qkv[rowbase + (size_t)j * QKVN + 2 * DMODEL]);
    }
    acc *= (1.0f / (float)n);
  } else {
    float qd = bf2f(qkv[rowbase + (size_t)i * QKVN]);
    for (int c = 0; c < n; c++) {
      int j = cj[c];
      float kd = bf2f(qkv[rowbase + (size_t)j * QKVN + DMODEL]);
      float p = qd * kd;
      #pragma unroll
      for (int o = 32; o > 0; o >>= 1) p += __shfl_xor(p, o);
      if (lane == 0) sw[c] = 3.0f * (p * 0.125f);
    }
    __syncthreads();
    float m = -1e30f;
    for (int c = 0; c < n; c++) m = fmaxf(m, sw[c]);
    float denom = 0.0f;
    for (int c = 0; c < n; c++) {
      int j = cj[c];
      float w = expf(sw[c] - m);
      denom += w;
      acc += w * bf2f(qkv[rowbase + (size_t)j * QKVN + 2 * DMODEL]);
    }
    acc /= denom;
  }
  ao[(size_t)(b * SEQ_ + i) * DMODEL + h * HDIM + lane] = f2bf(acc);
}

extern "C" void kernel_launch(void* const* d_in, const int* in_sizes, int n_in,
                              void* d_out, int out_size, void* d_ws, size_t ws_size,
                              hipStream_t stream) {
  const float* x     = (const float*)d_in[0];
  const float* w_qkv = (const float*)d_in[1];
  const float* w_out = (const float*)d_in[2];
  const float* gamma = (const float*)d_in[3];
  const float* beta  = (const float*)d_in[4];
  const int*   ridx  = (const int*)d_in[5];
  float* out = (float*)d_out;

  char* ws = (char*)d_ws;
  size_t off = 0;
  auto alloc = [&](size_t bytes) {
    char* p = ws + off;
    off = (off + bytes + 255) & ~(size_t)255;
    return p;
  };
  unsigned short* xn  = (unsigned short*)alloc((size_t)ROWS * DMODEL * 2);   // 8 MB
  unsigned short* wqb = (unsigned short*)alloc((size_t)DMODEL * QKVN * 2);   // 6 MB
  unsigned short* wob = (unsigned short*)alloc((size_t)DMODEL * DMODEL * 2); // 2 MB
  unsigned short* qkv = (unsigned short*)alloc((size_t)ROWS * QKVN * 2);     // 24 MB
  unsigned short* ao  = (unsigned short*)alloc((size_t)ROWS * DMODEL * 2);   // 8 MB
  int* cols = (int*)alloc((size_t)SEQ_ * 128 * 4);                           // 1 MB
  int* cnt  = (int*)alloc((size_t)SEQ_ * 4);
  int* tmx  = (int*)alloc((size_t)SEQ_ * 4);

  hipLaunchKernelGGL(ln_kernel, dim3(ROWS), dim3(256), 0, stream, x, gamma, beta, xn);
  hipLaunchKernelGGL(cvt_kernel, dim3((DMODEL * QKVN / 4 + 255) / 256), dim3(256), 0, stream,
                     w_qkv, wqb, DMODEL * QKVN / 4);
  hipLaunchKernelGGL(cvt_kernel, dim3((DMODEL * DMODEL / 4 + 255) / 256), dim3(256), 0, stream,
                     w_out, wob, DMODEL * DMODEL / 4);
  hipLaunchKernelGGL(gemm_bf16, dim3(QKVN / 64, ROWS / 64), dim3(256), 0, stream,
                     xn, wqb, qkv, (float*)nullptr, (const float*)nullptr, ROWS, QKVN, DMODEL);
  hipLaunchKernelGGL(mask_rows, dim3(SEQ_), dim3(64), 0, stream, ridx, cols, cnt, tmx);
  hipLaunchKernelGGL(attn_sparse, dim3(SEQ_, BATCH_ * NHEADS), dim3(64), 0, stream,
                     qkv, cols, cnt, tmx, ao);
  hipLaunchKernelGGL(gemm_bf16, dim3(DMODEL / 64, ROWS / 64), dim3(256), 0, stream,
                     ao, wob, (unsigned short*)nullptr, out, x, ROWS, DMODEL, DMODEL);
}

// Round 2
// 200.565 us; speedup vs baseline: 1.5704x; 1.5704x over previous
//
#include <hip/hip_runtime.h>
#include <stdint.h>

typedef __attribute__((ext_vector_type(8))) short shortx8;
typedef __attribute__((ext_vector_type(4))) float floatx4;

static constexpr int SEQ_    = 2048;
static constexpr int DMODEL  = 1024;
static constexpr int HDIM    = 64;
static constexpr int BATCH_  = 2;
static constexpr int NHEADS  = 16;
static constexpr int WINDOW_ = 64;
static constexpr int GTOK    = 4;
static constexpr int RTOK    = 32;
static constexpr int ROWS    = BATCH_ * SEQ_;   // 4096
static constexpr int QKVN    = 3 * DMODEL;      // 3072

__device__ inline unsigned short f2bf(float f) {
  union { float f; unsigned int u; } x; x.f = f;
  unsigned int r = (x.u + 0x7FFFu + ((x.u >> 16) & 1u)) >> 16;
  return (unsigned short)r;
}
__device__ inline float bf2f(unsigned short b) {
  union { unsigned int u; float f; } x; x.u = ((unsigned int)b) << 16;
  return x.f;
}

__device__ inline void gload_lds16(const void* g, void* l) {
  __builtin_amdgcn_global_load_lds(
      (const __attribute__((address_space(1))) void*)g,
      (__attribute__((address_space(3))) void*)l, 16, 0, 0);
}

// ---------------- LayerNorm -> bf16 ----------------
__global__ __launch_bounds__(256) void ln_kernel(const float* __restrict__ x,
    const float* __restrict__ gamma, const float* __restrict__ beta,
    unsigned short* __restrict__ xn) {
  int row = blockIdx.x;
  int t = threadIdx.x;
  const float4* xr = (const float4*)(x + (size_t)row * DMODEL);
  float4 v = xr[t];
  float s = v.x + v.y + v.z + v.w;
  #pragma unroll
  for (int o = 32; o > 0; o >>= 1) s += __shfl_xor(s, o);
  __shared__ float red[4];
  __shared__ float red2[4];
  int wave = t >> 6, lane = t & 63;
  if (lane == 0) red[wave] = s;
  __syncthreads();
  float mean = (red[0] + red[1] + red[2] + red[3]) * (1.0f / DMODEL);
  float dx = v.x - mean, dy = v.y - mean, dz = v.z - mean, dw = v.w - mean;
  float q = dx*dx + dy*dy + dz*dz + dw*dw;
  #pragma unroll
  for (int o = 32; o > 0; o >>= 1) q += __shfl_xor(q, o);
  if (lane == 0) red2[wave] = q;
  __syncthreads();
  float var = (red2[0] + red2[1] + red2[2] + red2[3]) * (1.0f / DMODEL);
  float rs = rsqrtf(var + 1e-5f);
  float4 g = ((const float4*)gamma)[t];
  float4 bb = ((const float4*)beta)[t];
  ushort4 outv;
  outv.x = f2bf(dx * rs * g.x + bb.x);
  outv.y = f2bf(dy * rs * g.y + bb.y);
  outv.z = f2bf(dz * rs * g.z + bb.z);
  outv.w = f2bf(dw * rs * g.w + bb.w);
  ((ushort4*)(xn + (size_t)row * DMODEL))[t] = outv;
}

// ---------------- transpose + convert: src[K][N] fp32 -> dst[N][K] bf16 ----------------
__global__ __launch_bounds__(256) void cvtT_kernel(const float* __restrict__ src,
    unsigned short* __restrict__ dst, int K, int N) {
  __shared__ float tile[32][33];
  int k0 = blockIdx.y * 32, n0 = blockIdx.x * 32;
  int tx = threadIdx.x & 31, ty = threadIdx.x >> 5;  // 32x8
  #pragma unroll
  for (int r = ty; r < 32; r += 8)
    tile[r][tx] = src[(size_t)(k0 + r) * N + n0 + tx];
  __syncthreads();
  #pragma unroll
  for (int r = ty; r < 32; r += 8)
    dst[(size_t)(n0 + r) * K + k0 + tx] = f2bf(tile[tx][r]);
}

// ---------------- m97-style bf16 MFMA GEMM ----------------
// C[MxN] = A[MxK] @ BT[NxK]^T (+resid). 128xBN tile, BK=32, 256 thr = 4 waves.
// Wave tile 64 x (BN/2): acc[4][BN/32] of 16x16x32 MFMA. global_load_lds w=16.
template <int BN>   // 128 or 64
__global__ __launch_bounds__(256) void gemm128(
    const unsigned short* __restrict__ A, const unsigned short* __restrict__ BT,
    unsigned short* __restrict__ Cb, float* __restrict__ Cf,
    const float* __restrict__ resid, int M, int N, int K) {
  constexpr int WN  = BN / 2;     // wave n-extent
  constexpr int NTN = WN / 16;    // n-subtiles per wave
  __shared__ unsigned short Al[128 * 32];
  __shared__ unsigned short Bl[BN * 32];
  const int bm = blockIdx.y * 128, bn = blockIdx.x * BN;
  const int tid = threadIdx.x;
  const int wave = tid >> 6, lane = tid & 63;
  const int wm = (wave >> 1) * 64, wn = (wave & 1) * WN;
  const int quad = lane >> 4, l16 = lane & 15;
  const int lrow = lane >> 2;          // 16 rows per 1KB chunk, 4 lanes/row
  const int lkoff = (lane & 3) * 8;    // 8 bf16 = 16B per lane
  floatx4 acc[4][NTN] = {};
  for (int k0 = 0; k0 < K; k0 += 32) {
    __syncthreads();   // prior ds_reads done before overwrite
    #pragma unroll
    for (int q = 0; q < 2; q++) {      // A: 128 rows, wave stages 32
      int r = wave * 32 + q * 16;
      gload_lds16(A + (size_t)(bm + r + lrow) * K + k0 + lkoff, Al + r * 32);
    }
    #pragma unroll
    for (int q = 0; q < BN / 64; q++) { // B: BN rows, wave stages BN/4
      int r = wave * (BN / 4) + q * 16;
      gload_lds16(BT + (size_t)(bn + r + lrow) * K + k0 + lkoff, Bl + r * 32);
    }
    __syncthreads();   // vmcnt(0) drain before barrier (compiler-inserted)
    shortx8 af[4], bfr[NTN];
    #pragma unroll
    for (int s = 0; s < 4; s++)
      af[s] = *(const shortx8*)&Al[(wm + s * 16 + l16) * 32 + quad * 8];
    #pragma unroll
    for (int s = 0; s < NTN; s++)
      bfr[s] = *(const shortx8*)&Bl[(wn + s * 16 + l16) * 32 + quad * 8];
    #pragma unroll
    for (int sm = 0; sm < 4; sm++)
      #pragma unroll
      for (int sn = 0; sn < NTN; sn++)
        acc[sm][sn] = __builtin_amdgcn_mfma_f32_16x16x32_bf16(af[sm], bfr[sn], acc[sm][sn], 0, 0, 0);
  }
  #pragma unroll
  for (int sm = 0; sm < 4; sm++)
    #pragma unroll
    for (int sn = 0; sn < NTN; sn++)
      #pragma unroll
      for (int r = 0; r < 4; r++) {
        int row = bm + wm + sm * 16 + quad * 4 + r;
        int col = bn + wn + sn * 16 + l16;
        size_t off = (size_t)row * N + col;
        float v = acc[sm][sn][r];
        if (resid) v += resid[off];
        if (Cf) Cf[off] = v;
        else    Cb[off] = f2bf(v);
      }
}

// ---------------- per-row top-tier mask column lists ----------------
__global__ __launch_bounds__(64) void mask_rows(const int* __restrict__ rand_idx,
    int* __restrict__ cols, int* __restrict__ cnt, int* __restrict__ tmx) {
  const int i = blockIdx.x;
  const int lane = threadIdx.x;
  __shared__ int rl[RTOK];
  __shared__ int scount;
  if (lane < RTOK) rl[lane] = rand_idx[i * RTOK + lane];
  if (lane == 0) scount = 0;
  __syncthreads();
  const int wstart = (i - WINDOW_ > 0) ? (i - WINDOW_) : 0;
  int jj[2]; int tt[2];
  #pragma unroll
  for (int p = 0; p < 2; p++) {
    int c = lane + p * 64;
    int j = -1;
    bool valid = false;
    if (c < 65) {
      j = i - WINDOW_ + c;
      valid = (j >= 0);
    } else if (c < 73) {
      int g = c - 65;
      j = (g < 4) ? g : (SEQ_ - 8 + g);
      valid = (j <= i) && (j < wstart);
    } else if (c < 73 + RTOK) {
      int r = c - 73;
      j = rl[r];
      bool dup = false;
      for (int r2 = 0; r2 < r; r2++) dup = dup || (rl[r2] == j);
      valid = (j <= i) && (j < wstart) && !(j < GTOK || j >= SEQ_ - GTOK) && !dup;
    }
    int t = -1;
    if (valid) {
      int loc = ((i - j) <= WINDOW_) ? 1 : 0;
      int glb = (j < GTOK || j >= SEQ_ - GTOK) ? 1 : 0;
      int rnd = 0;
      for (int r = 0; r < RTOK; r++) rnd |= (rl[r] == j) ? 1 : 0;
      t = loc + glb + rnd;
    }
    jj[p] = j; tt[p] = t;
  }
  int tm = (tt[0] > tt[1]) ? tt[0] : tt[1];
  #pragma unroll
  for (int o = 1; o < 64; o <<= 1) {
    int other = __shfl_xor(tm, o);
    tm = (other > tm) ? other : tm;
  }
  #pragma unroll
  for (int p = 0; p < 2; p++) {
    if (tt[p] == tm) {
      int pos = atomicAdd(&scount, 1);
      cols[i * 128 + pos] = jj[p];
    }
  }
  __syncthreads();
  if (lane == 0) { cnt[i] = scount; tmx[i] = tm; }
}

// ---------------- sparse attention v2: one block per (b,row), all 16 heads ----------------
__global__ __launch_bounds__(256) void attn_v2(
    const unsigned short* __restrict__ qkv, const int* __restrict__ cols,
    const int* __restrict__ cnt, const int* __restrict__ tmx,
    unsigned short* __restrict__ ao) {
  const int i = blockIdx.x, b = blockIdx.y;
  const int t = threadIdx.x;
  const int n = cnt[i], tm = tmx[i];
  __shared__ int cj[128];
  __shared__ float sw[4][128];
  for (int c = t; c < n; c += 256) cj[c] = cols[i * 128 + c];
  __syncthreads();
  const size_t base = (size_t)(b * SEQ_) * QKVN;
  if (tm < 3) {
    // exact fp32 semantics: uniform over top-tier columns; V only.
    float ax = 0.f, ay = 0.f, az = 0.f, aw = 0.f;
    for (int c = 0; c < n; c++) {
      ushort4 v = ((const ushort4*)(qkv + base + (size_t)cj[c] * QKVN + 2 * DMODEL))[t];
      ax += bf2f(v.x); ay += bf2f(v.y); az += bf2f(v.z); aw += bf2f(v.w);
    }
    float inv = 1.0f / (float)n;
    ushort4 o;
    o.x = f2bf(ax * inv); o.y = f2bf(ay * inv);
    o.z = f2bf(az * inv); o.w = f2bf(aw * inv);
    ((ushort4*)(ao + (size_t)(b * SEQ_ + i) * DMODEL))[t] = o;
  } else {
    // rare tier-3 rows: true softmax of 3*qk/8 per head. wave w -> heads w, w+4, ...
    const int wave = t >> 6, lane = t & 63;
    for (int h = wave; h < NHEADS; h += 4) {
      const size_t rb = base + (size_t)h * HDIM + lane;
      float qd = bf2f(qkv[rb + (size_t)i * QKVN]);
      float m = -1e30f;
      for (int c = 0; c < n; c++) {
        float kd = bf2f(qkv[rb + (size_t)cj[c] * QKVN + DMODEL]);
        float p = qd * kd;
        #pragma unroll
        for (int o = 32; o > 0; o >>= 1) p += __shfl_xor(p, o);
        p *= 0.375f;   // 3 * (qk/8)
        sw[wave][c] = p;
        m = fmaxf(m, p);
      }
      float denom = 0.f, acc = 0.f;
      for (int c = 0; c < n; c++) {
        float w = __expf(sw[wave][c] - m);
        denom += w;
        acc += w * bf2f(qkv[rb + (size_t)cj[c] * QKVN + 2 * DMODEL]);
      }
      ao[(size_t)(b * SEQ_ + i) * DMODEL + h * HDIM + lane] = f2bf(acc / denom);
    }
  }
}

extern "C" void kernel_launch(void* const* d_in, const int* in_sizes, int n_in,
                              void* d_out, int out_size, void* d_ws, size_t ws_size,
                              hipStream_t stream) {
  const float* x     = (const float*)d_in[0];
  const float* w_qkv = (const float*)d_in[1];
  const float* w_out = (const float*)d_in[2];
  const float* gamma = (const float*)d_in[3];
  const float* beta  = (const float*)d_in[4];
  const int*   ridx  = (const int*)d_in[5];
  float* out = (float*)d_out;

  char* ws = (char*)d_ws;
  size_t off = 0;
  auto alloc = [&](size_t bytes) {
    char* p = ws + off;
    off = (off + bytes + 255) & ~(size_t)255;
    return p;
  };
  unsigned short* xn   = (unsigned short*)alloc((size_t)ROWS * DMODEL * 2);   // 8 MB
  unsigned short* wqT  = (unsigned short*)alloc((size_t)QKVN * DMODEL * 2);   // 6 MB (N x K)
  unsigned short* woT  = (unsigned short*)alloc((size_t)DMODEL * DMODEL * 2); // 2 MB (N x K)
  unsigned short* qkv  = (unsigned short*)alloc((size_t)ROWS * QKVN * 2);     // 24 MB
  unsigned short* ao   = (unsigned short*)alloc((size_t)ROWS * DMODEL * 2);   // 8 MB
  int* cols = (int*)alloc((size_t)SEQ_ * 128 * 4);                            // 1 MB
  int* cnt  = (int*)alloc((size_t)SEQ_ * 4);
  int* tmx  = (int*)alloc((size_t)SEQ_ * 4);

  hipLaunchKernelGGL(ln_kernel, dim3(ROWS), dim3(256), 0, stream, x, gamma, beta, xn);
  hipLaunchKernelGGL(cvtT_kernel, dim3(QKVN / 32, DMODEL / 32), dim3(256), 0, stream,
                     w_qkv, wqT, DMODEL, QKVN);
  hipLaunchKernelGGL(cvtT_kernel, dim3(DMODEL / 32, DMODEL / 32), dim3(256), 0, stream,
                     w_out, woT, DMODEL, DMODEL);
  hipLaunchKernelGGL(HIP_KERNEL_NAME(gemm128<128>), dim3(QKVN / 128, ROWS / 128), dim3(256), 0, stream,
                     xn, wqT, qkv, (float*)nullptr, (const float*)nullptr, ROWS, QKVN, DMODEL);
  hipLaunchKernelGGL(mask_rows, dim3(SEQ_), dim3(64), 0, stream, ridx, cols, cnt, tmx);
  hipLaunchKernelGGL(attn_v2, dim3(SEQ_, BATCH_), dim3(256), 0, stream,
                     qkv, cols, cnt, tmx, ao);
  hipLaunchKernelGGL(HIP_KERNEL_NAME(gemm128<64>), dim3(DMODEL / 64, ROWS / 128), dim3(256), 0, stream,
                     ao, woT, (unsigned short*)nullptr, out, x, ROWS, DMODEL, DMODEL);
}